// Round 6
// baseline (328.101 us; speedup 1.0000x reference)
//
#include <hip/hip_runtime.h>
#include <hip/hip_bf16.h>

// MDN: B=65536, COND=32, D=16, H=256, K=16
//  pi    = softmax(z @ Wpi + bpi)            [B,16]
//  sigma = diag_embed(exp(z @ Wsig + bsig))  [B,16,16,16]
//  mu    = z @ Wmu + bmu                     [B,16,16]
//  z = tanh(x @ W1 + b1)                     [B,256]
//
// Write-bound: 1.145 GB output => ~176 us floor at 6.5 TB/s.
// R2: lane-contiguous stores via wave-private LDS bounce. 248 us.
// R3: nt A/B -> identical (248). R4: wave-specialized/TB=32 -> 264 (reverted).
// R5: two-kernel split. K1 = compact compute (diag values 64MB to ws, mu, pi).
// K2 = pure expansion (fillBuffer-shaped: sequential 1KB stores, no LDS/MFMA,
// ~6 instrs per KB). Diagnostic: if K2 streams at ~6.3 TB/s, total ~215us;
// if K2 matches R3's 4.6 TB/s the write ceiling is pattern-independent.
// Falls back to the R3 kernel when ws_size < 67.4 MB.

typedef __attribute__((ext_vector_type(8))) short short8;   // 8 bf16
typedef __attribute__((ext_vector_type(4))) float f32x4;

#define NB 65536
#define TB 64          // batch rows per block
#define HID 256
#define CIN 32

// ws layout (bf16): wpi_t [16][256] | wsig_t [256][256] | wmu_t [256][256]
// then (f32, 2-kernel path only): sigma_diag [65536][256]
#define WPI_OFF  0
#define WSIG_OFF (16*256)
#define WMU_OFF  (16*256 + 256*256)
#define WS_WEIGHT_BYTES 270336
#define WS_DIAG_BYTES   ((size_t)NB*256*4)

__global__ __launch_bounds__(256) void cvt_weights(
    const float* __restrict__ Wpi, const float* __restrict__ Wsig,
    const float* __restrict__ Wmu, __hip_bfloat16* __restrict__ wsb)
{
    int r = blockIdx.x;      // 0..527 = output col -> transposed row
    int k = threadIdx.x;     // 0..255 = H index
    if (r < 16)
        wsb[WPI_OFF + r*256 + k] = __float2bfloat16(Wpi[k*16 + r]);
    else if (r < 272)
        wsb[WSIG_OFF + (r-16)*256 + k] = __float2bfloat16(Wsig[k*256 + (r-16)]);
    else
        wsb[WMU_OFF + (r-272)*256 + k] = __float2bfloat16(Wmu[k*256 + (r-272)]);
}

// ---------------------------------------------------------------------------
// Shared body for the compute kernel. EXPAND_SIGMA=1 reproduces R3 exactly
// (full in-kernel sigma expansion); EXPAND_SIGMA=0 writes compact diag to ws.
// ---------------------------------------------------------------------------
template <int EXPAND_SIGMA>
__device__ __forceinline__ void mdn_body(
    const float* __restrict__ x, const float* __restrict__ W1,
    const float* __restrict__ b1, const float* __restrict__ bpi,
    const float* __restrict__ bsig, const float* __restrict__ bmu,
    const __hip_bfloat16* __restrict__ wsb,
    float* __restrict__ diag,          // used when EXPAND_SIGMA==0
    float* __restrict__ out)
{
    __shared__ alignas(16) __hip_bfloat16 zs[TB][264];
    __shared__ alignas(16) float scratch[4][32][40];   // per-wave [32 rows][32 cols + pad]

    const int t  = threadIdx.x;
    const int b0 = blockIdx.x * TB;

    float* out_pi  = out;
    float* out_sig = out + (size_t)NB*16;
    float* out_mu  = out + (size_t)NB*16 + (size_t)NB*4096;

    // ---- load x tile [64][32] into scratch-as-xs (coalesced float4) ----
    float* xs = &scratch[0][0][0];   // 8KB, dead after z-phase
    {
        const float4* gx4 = reinterpret_cast<const float4*>(x + (size_t)b0*CIN);
        float4* xs4 = reinterpret_cast<float4*>(xs);
        xs4[t]       = gx4[t];
        xs4[t + 256] = gx4[t + 256];
    }

    // ---- preload W1 column t ----
    float w1c[CIN];
    #pragma unroll
    for (int c = 0; c < CIN; c++) w1c[c] = W1[c*HID + t];
    const float b1t = b1[t];
    __syncthreads();

    // ---- z = tanh(x @ W1 + b1), thread t owns hidden unit t ----
    for (int r = 0; r < TB; r += 4) {
        float a0 = b1t, a1 = b1t, a2 = b1t, a3 = b1t;
        const float4* x0 = reinterpret_cast<const float4*>(xs + (r+0)*CIN);
        const float4* x1 = reinterpret_cast<const float4*>(xs + (r+1)*CIN);
        const float4* x2 = reinterpret_cast<const float4*>(xs + (r+2)*CIN);
        const float4* x3 = reinterpret_cast<const float4*>(xs + (r+3)*CIN);
        #pragma unroll
        for (int c4 = 0; c4 < CIN/4; c4++) {
            float4 v0 = x0[c4], v1 = x1[c4], v2 = x2[c4], v3 = x3[c4];
            float w0 = w1c[c4*4+0], w1 = w1c[c4*4+1], w2 = w1c[c4*4+2], w3 = w1c[c4*4+3];
            a0 += v0.x*w0; a0 += v0.y*w1; a0 += v0.z*w2; a0 += v0.w*w3;
            a1 += v1.x*w0; a1 += v1.y*w1; a1 += v1.z*w2; a1 += v1.w*w3;
            a2 += v2.x*w0; a2 += v2.y*w1; a2 += v2.z*w2; a2 += v2.w*w3;
            a3 += v3.x*w0; a3 += v3.y*w1; a3 += v3.z*w2; a3 += v3.w*w3;
        }
        zs[r+0][t] = __float2bfloat16(1.0f - 2.0f/(__expf(2.0f*a0)+1.0f));
        zs[r+1][t] = __float2bfloat16(1.0f - 2.0f/(__expf(2.0f*a1)+1.0f));
        zs[r+2][t] = __float2bfloat16(1.0f - 2.0f/(__expf(2.0f*a2)+1.0f));
        zs[r+3][t] = __float2bfloat16(1.0f - 2.0f/(__expf(2.0f*a3)+1.0f));
    }
    __syncthreads();
    // ======== no block barriers below this line ========

    const int w    = t >> 6;       // wave 0..3
    const int lane = t & 63;
    const int wm   = w >> 1;       // wave row 0..1  (32 batch rows each)
    const int wn   = w & 1;        // wave col 0..1  (32 out cols each)
    const int lr   = lane & 15;
    const int lk   = lane >> 4;

    const short8* A0 = reinterpret_cast<const short8*>(&zs[wm*32 +      lr][0]);
    const short8* A1 = reinterpret_cast<const short8*>(&zs[wm*32 + 16 + lr][0]);
    float* scr = &scratch[w][0][0];          // wave-private [32][40]

    // sigma fill-phase lane roles (expand path)
    const int cidx = lane >> 2;
    const int q    = lane & 3;
    const int epos = cidx - 4*q;
    // compact-diag lane roles
    const int r2  = lane >> 5;               // 0/1
    const int cc  = lane & 31;               // col 0..31
    // mu fill-phase lane roles
    const int mrr = lane >> 3;               // 0..7
    const int mcc = (lane & 7) * 4;

    f32x4* const sig4 = reinterpret_cast<f32x4*>(out_sig);
    f32x4* const mu4  = reinterpret_cast<f32x4*>(out_mu);

    for (int chunk = 0; chunk < 8; chunk++) {
        const bool is_sig = (chunk < 4);
        const int c0 = (chunk & 3) * 64;
        const __hip_bfloat16* wbase =
            wsb + (is_sig ? WSIG_OFF : WMU_OFF) + (size_t)c0*256;
        const short8* B0 = reinterpret_cast<const short8*>(wbase + (wn*32 +      lr)*256);
        const short8* B1 = reinterpret_cast<const short8*>(wbase + (wn*32 + 16 + lr)*256);

        f32x4 acc[2][2] = {};
        #pragma unroll
        for (int kk = 0; kk < 8; kk++) {
            const int fi = kk*4 + lk;
            short8 af0 = A0[fi];
            short8 af1 = A1[fi];
            short8 bf0 = B0[fi];
            short8 bf1 = B1[fi];
            acc[0][0] = __builtin_amdgcn_mfma_f32_16x16x32_bf16(af0, bf0, acc[0][0], 0,0,0);
            acc[0][1] = __builtin_amdgcn_mfma_f32_16x16x32_bf16(af0, bf1, acc[0][1], 0,0,0);
            acc[1][0] = __builtin_amdgcn_mfma_f32_16x16x32_bf16(af1, bf0, acc[1][0], 0,0,0);
            acc[1][1] = __builtin_amdgcn_mfma_f32_16x16x32_bf16(af1, bf1, acc[1][1], 0,0,0);
        }

        // WAR: previous chunk's scr reads must be done
        asm volatile("s_waitcnt lgkmcnt(0)" ::: "memory");

        // ---- stage this wave's 32x32 value tile into private scratch ----
        #pragma unroll
        for (int ni = 0; ni < 2; ni++) {
            const int c = c0 + wn*32 + ni*16 + lr;
            const float bias = is_sig ? bsig[c] : bmu[c];
            #pragma unroll
            for (int mi = 0; mi < 2; mi++) {
                #pragma unroll
                for (int j = 0; j < 4; j++) {
                    const int row = mi*16 + lk*4 + j;
                    const int col = ni*16 + lr;
                    float v = acc[mi][ni][j] + bias;
                    scr[row*40 + col] = is_sig ? __expf(v) : v;
                }
            }
        }
        asm volatile("s_waitcnt lgkmcnt(0)" ::: "memory");

        if (is_sig) {
            if (EXPAND_SIGMA) {
                // per (r, cb): 64 lanes x 16B = 1KB contiguous
                #pragma unroll 4
                for (int r = 0; r < 32; r++) {
                    size_t base = (size_t)(b0 + wm*32 + r) * 1024
                                + (size_t)(c0 + wn*32) * 4 + lane;
                    #pragma unroll
                    for (int cb = 0; cb < 2; cb++) {
                        float val = scr[r*40 + cb*16 + cidx];
                        f32x4 v;
                        v[0] = (epos == 0) ? val : 0.0f;
                        v[1] = (epos == 1) ? val : 0.0f;
                        v[2] = (epos == 2) ? val : 0.0f;
                        v[3] = (epos == 3) ? val : 0.0f;
                        sig4[base + cb*64] = v;
                    }
                }
            } else {
                // compact: wave's 32 rows x 32 cols -> diag[b][c], 2 rows/instr
                float* dbase = diag + (size_t)(b0 + wm*32)*256 + c0 + wn*32 + cc;
                #pragma unroll
                for (int rr = 0; rr < 16; rr++) {
                    const int row = rr*2 + r2;
                    dbase[(size_t)row*256] = scr[row*40 + cc];
                }
            }
        } else {
            // mu: per it 8 rows x 128B segments, full lines
            #pragma unroll
            for (int it = 0; it < 4; it++) {
                const int r = it*8 + mrr;
                f32x4 v = *reinterpret_cast<const f32x4*>(&scr[r*40 + mcc]);
                size_t base = (size_t)(b0 + wm*32 + r) * 64
                            + (size_t)(c0 + wn*32) / 4 + (lane & 7);
                mu4[base] = v;
            }
        }
    }

    // ---- pi ----
    {
        const short8* Ap = reinterpret_cast<const short8*>(&zs[w*16 + lr][0]);
        const short8* Bp = reinterpret_cast<const short8*>(wsb + WPI_OFF + lr*256);

        f32x4 pacc = {};
        #pragma unroll
        for (int kk = 0; kk < 8; kk++) {
            short8 af = Ap[kk*4 + lk];
            short8 bf = Bp[kk*4 + lk];
            pacc = __builtin_amdgcn_mfma_f32_16x16x32_bf16(af, bf, pacc, 0,0,0);
        }
        const float bp = bpi[lr];
        #pragma unroll
        for (int j = 0; j < 4; j++) {
            float v = pacc[j] + bp;
            float m = v;
            m = fmaxf(m, __shfl_xor(m, 1));
            m = fmaxf(m, __shfl_xor(m, 2));
            m = fmaxf(m, __shfl_xor(m, 4));
            m = fmaxf(m, __shfl_xor(m, 8));
            float e = __expf(v - m);
            float s = e;
            s += __shfl_xor(s, 1);
            s += __shfl_xor(s, 2);
            s += __shfl_xor(s, 4);
            s += __shfl_xor(s, 8);
            const int b = b0 + w*16 + lk*4 + j;
            out_pi[(size_t)b*16 + lr] = e / s;
        }
    }
}

__global__ __launch_bounds__(256, 3) void mdn_full(
    const float* __restrict__ x, const float* __restrict__ W1,
    const float* __restrict__ b1, const float* __restrict__ bpi,
    const float* __restrict__ bsig, const float* __restrict__ bmu,
    const __hip_bfloat16* __restrict__ wsb, float* __restrict__ out)
{
    mdn_body<1>(x, W1, b1, bpi, bsig, bmu, wsb, nullptr, out);
}

__global__ __launch_bounds__(256, 3) void mdn_compact(
    const float* __restrict__ x, const float* __restrict__ W1,
    const float* __restrict__ b1, const float* __restrict__ bpi,
    const float* __restrict__ bsig, const float* __restrict__ bmu,
    const __hip_bfloat16* __restrict__ wsb, float* __restrict__ diag,
    float* __restrict__ out)
{
    mdn_body<0>(x, W1, b1, bpi, bsig, bmu, wsb, diag, out);
}

// ---------------------------------------------------------------------------
// K2: pure expansion. Each wave: 8 rows x 16KB fully sequential. Per 1KB
// store: 1 broadcast load + 4 cndmask + 1 dwordx4 store.
// ---------------------------------------------------------------------------
__global__ __launch_bounds__(256) void sigma_expand(
    const float* __restrict__ diag, float* __restrict__ out_sig)
{
    const int t = threadIdx.x;
    const int w = t >> 6, lane = t & 63;
    const int i    = lane >> 2;              // sigma row index within 16x16
    const int epos = i - 4*(lane & 3);       // nonzero slot if in [0,4)
    const int b_base = blockIdx.x * 32 + w * 8;

    f32x4* const sig4 = reinterpret_cast<f32x4*>(out_sig);

    for (int rr = 0; rr < 8; rr++) {
        const int b = b_base + rr;
        const float* drow = diag + (size_t)b*256 + i;
        const size_t o4 = (size_t)b*1024 + lane;
        #pragma unroll
        for (int qq = 0; qq < 16; qq++) {    // qq = mixture k
            const float val = drow[qq*16];
            f32x4 v;
            v[0] = (epos == 0) ? val : 0.0f;
            v[1] = (epos == 1) ? val : 0.0f;
            v[2] = (epos == 2) ? val : 0.0f;
            v[3] = (epos == 3) ? val : 0.0f;
            sig4[o4 + qq*64] = v;
        }
    }
}

extern "C" void kernel_launch(void* const* d_in, const int* in_sizes, int n_in,
                              void* d_out, int out_size, void* d_ws, size_t ws_size,
                              hipStream_t stream) {
    (void)in_sizes; (void)n_in; (void)out_size;
    const float* x    = (const float*)d_in[0];
    const float* W1   = (const float*)d_in[1];
    const float* b1   = (const float*)d_in[2];
    const float* Wpi  = (const float*)d_in[3];
    const float* bpi  = (const float*)d_in[4];
    const float* Wsig = (const float*)d_in[5];
    const float* bsig = (const float*)d_in[6];
    const float* Wmu  = (const float*)d_in[7];
    const float* bmu  = (const float*)d_in[8];
    float* out = (float*)d_out;
    __hip_bfloat16* wsb = (__hip_bfloat16*)d_ws;

    cvt_weights<<<528, 256, 0, stream>>>(Wpi, Wsig, Wmu, wsb);

    if (ws_size >= WS_WEIGHT_BYTES + WS_DIAG_BYTES) {
        float* diag = (float*)((char*)d_ws + WS_WEIGHT_BYTES);
        mdn_compact<<<NB/TB, 256, 0, stream>>>(x, W1, b1, bpi, bsig, bmu,
                                               wsb, diag, out);
        sigma_expand<<<NB/32, 256, 0, stream>>>(diag, out + (size_t)NB*16);
    } else {
        mdn_full<<<NB/TB, 256, 0, stream>>>(x, W1, b1, bpi, bsig, bmu,
                                            wsb, out);
    }
}

// Round 7
// 326.219 us; speedup vs baseline: 1.0058x; 1.0058x over previous
//
#include <hip/hip_runtime.h>
#include <hip/hip_bf16.h>

// MDN: B=65536, COND=32, D=16, H=256, K=16
//  pi    = softmax(z @ Wpi + bpi)            [B,16]
//  sigma = diag_embed(exp(z @ Wsig + bsig))  [B,16,16,16]
//  mu    = z @ Wmu + bmu                     [B,16,16]
//  z = tanh(x @ W1 + b1)                     [B,256]
//
// Write-bound: 1.145 GB output => ~176 us floor at 6.5 TB/s.
// R2 fused lane-contiguous stores: 248 us (4.65 TB/s effective).
// R3 nt A/B: null. R4 burst/phase shaping: -6% (reverted).
// R5 split: K2 (2048 blk, 8192 x 128KB streams) ~4.2 TB/s -> 328 us.
// R6: K2 with fillBuffer-like stream structure: 512 blocks x 4 waves =
// 2048 streams x 512KB sequential each, next-row prefetch. Tests whether
// HBM write efficiency is governed by stream count/length.

typedef __attribute__((ext_vector_type(8))) short short8;   // 8 bf16
typedef __attribute__((ext_vector_type(4))) float f32x4;

#define NB 65536
#define TB 64          // batch rows per block
#define HID 256
#define CIN 32

// ws layout (bf16): wpi_t [16][256] | wsig_t [256][256] | wmu_t [256][256]
// then (f32, 2-kernel path only): sigma_diag [65536][256]
#define WPI_OFF  0
#define WSIG_OFF (16*256)
#define WMU_OFF  (16*256 + 256*256)
#define WS_WEIGHT_BYTES 270336
#define WS_DIAG_BYTES   ((size_t)NB*256*4)

__global__ __launch_bounds__(256) void cvt_weights(
    const float* __restrict__ Wpi, const float* __restrict__ Wsig,
    const float* __restrict__ Wmu, __hip_bfloat16* __restrict__ wsb)
{
    int r = blockIdx.x;      // 0..527 = output col -> transposed row
    int k = threadIdx.x;     // 0..255 = H index
    if (r < 16)
        wsb[WPI_OFF + r*256 + k] = __float2bfloat16(Wpi[k*16 + r]);
    else if (r < 272)
        wsb[WSIG_OFF + (r-16)*256 + k] = __float2bfloat16(Wsig[k*256 + (r-16)]);
    else
        wsb[WMU_OFF + (r-272)*256 + k] = __float2bfloat16(Wmu[k*256 + (r-272)]);
}

// ---------------------------------------------------------------------------
// Compute body. EXPAND_SIGMA=1 == R3 fused kernel; EXPAND_SIGMA=0 writes
// compact diag to ws.
// ---------------------------------------------------------------------------
template <int EXPAND_SIGMA>
__device__ __forceinline__ void mdn_body(
    const float* __restrict__ x, const float* __restrict__ W1,
    const float* __restrict__ b1, const float* __restrict__ bpi,
    const float* __restrict__ bsig, const float* __restrict__ bmu,
    const __hip_bfloat16* __restrict__ wsb,
    float* __restrict__ diag,          // used when EXPAND_SIGMA==0
    float* __restrict__ out)
{
    __shared__ alignas(16) __hip_bfloat16 zs[TB][264];
    __shared__ alignas(16) float scratch[4][32][40];   // per-wave [32 rows][32 cols + pad]

    const int t  = threadIdx.x;
    const int b0 = blockIdx.x * TB;

    float* out_pi  = out;
    float* out_sig = out + (size_t)NB*16;
    float* out_mu  = out + (size_t)NB*16 + (size_t)NB*4096;

    // ---- load x tile [64][32] into scratch-as-xs (coalesced float4) ----
    float* xs = &scratch[0][0][0];   // 8KB, dead after z-phase
    {
        const float4* gx4 = reinterpret_cast<const float4*>(x + (size_t)b0*CIN);
        float4* xs4 = reinterpret_cast<float4*>(xs);
        xs4[t]       = gx4[t];
        xs4[t + 256] = gx4[t + 256];
    }

    // ---- preload W1 column t ----
    float w1c[CIN];
    #pragma unroll
    for (int c = 0; c < CIN; c++) w1c[c] = W1[c*HID + t];
    const float b1t = b1[t];
    __syncthreads();

    // ---- z = tanh(x @ W1 + b1), thread t owns hidden unit t ----
    for (int r = 0; r < TB; r += 4) {
        float a0 = b1t, a1 = b1t, a2 = b1t, a3 = b1t;
        const float4* x0 = reinterpret_cast<const float4*>(xs + (r+0)*CIN);
        const float4* x1 = reinterpret_cast<const float4*>(xs + (r+1)*CIN);
        const float4* x2 = reinterpret_cast<const float4*>(xs + (r+2)*CIN);
        const float4* x3 = reinterpret_cast<const float4*>(xs + (r+3)*CIN);
        #pragma unroll
        for (int c4 = 0; c4 < CIN/4; c4++) {
            float4 v0 = x0[c4], v1 = x1[c4], v2 = x2[c4], v3 = x3[c4];
            float w0 = w1c[c4*4+0], w1 = w1c[c4*4+1], w2 = w1c[c4*4+2], w3 = w1c[c4*4+3];
            a0 += v0.x*w0; a0 += v0.y*w1; a0 += v0.z*w2; a0 += v0.w*w3;
            a1 += v1.x*w0; a1 += v1.y*w1; a1 += v1.z*w2; a1 += v1.w*w3;
            a2 += v2.x*w0; a2 += v2.y*w1; a2 += v2.z*w2; a2 += v2.w*w3;
            a3 += v3.x*w0; a3 += v3.y*w1; a3 += v3.z*w2; a3 += v3.w*w3;
        }
        zs[r+0][t] = __float2bfloat16(1.0f - 2.0f/(__expf(2.0f*a0)+1.0f));
        zs[r+1][t] = __float2bfloat16(1.0f - 2.0f/(__expf(2.0f*a1)+1.0f));
        zs[r+2][t] = __float2bfloat16(1.0f - 2.0f/(__expf(2.0f*a2)+1.0f));
        zs[r+3][t] = __float2bfloat16(1.0f - 2.0f/(__expf(2.0f*a3)+1.0f));
    }
    __syncthreads();
    // ======== no block barriers below this line ========

    const int w    = t >> 6;       // wave 0..3
    const int lane = t & 63;
    const int wm   = w >> 1;       // wave row 0..1  (32 batch rows each)
    const int wn   = w & 1;        // wave col 0..1  (32 out cols each)
    const int lr   = lane & 15;
    const int lk   = lane >> 4;

    const short8* A0 = reinterpret_cast<const short8*>(&zs[wm*32 +      lr][0]);
    const short8* A1 = reinterpret_cast<const short8*>(&zs[wm*32 + 16 + lr][0]);
    float* scr = &scratch[w][0][0];          // wave-private [32][40]

    // sigma fill-phase lane roles (expand path)
    const int cidx = lane >> 2;
    const int q    = lane & 3;
    const int epos = cidx - 4*q;
    // compact-diag lane roles
    const int r2  = lane >> 5;               // 0/1
    const int cc  = lane & 31;               // col 0..31
    // mu fill-phase lane roles
    const int mrr = lane >> 3;               // 0..7
    const int mcc = (lane & 7) * 4;

    f32x4* const sig4 = reinterpret_cast<f32x4*>(out_sig);
    f32x4* const mu4  = reinterpret_cast<f32x4*>(out_mu);

    for (int chunk = 0; chunk < 8; chunk++) {
        const bool is_sig = (chunk < 4);
        const int c0 = (chunk & 3) * 64;
        const __hip_bfloat16* wbase =
            wsb + (is_sig ? WSIG_OFF : WMU_OFF) + (size_t)c0*256;
        const short8* B0 = reinterpret_cast<const short8*>(wbase + (wn*32 +      lr)*256);
        const short8* B1 = reinterpret_cast<const short8*>(wbase + (wn*32 + 16 + lr)*256);

        f32x4 acc[2][2] = {};
        #pragma unroll
        for (int kk = 0; kk < 8; kk++) {
            const int fi = kk*4 + lk;
            short8 af0 = A0[fi];
            short8 af1 = A1[fi];
            short8 bf0 = B0[fi];
            short8 bf1 = B1[fi];
            acc[0][0] = __builtin_amdgcn_mfma_f32_16x16x32_bf16(af0, bf0, acc[0][0], 0,0,0);
            acc[0][1] = __builtin_amdgcn_mfma_f32_16x16x32_bf16(af0, bf1, acc[0][1], 0,0,0);
            acc[1][0] = __builtin_amdgcn_mfma_f32_16x16x32_bf16(af1, bf0, acc[1][0], 0,0,0);
            acc[1][1] = __builtin_amdgcn_mfma_f32_16x16x32_bf16(af1, bf1, acc[1][1], 0,0,0);
        }

        // WAR: previous chunk's scr reads must be done
        asm volatile("s_waitcnt lgkmcnt(0)" ::: "memory");

        // ---- stage this wave's 32x32 value tile into private scratch ----
        #pragma unroll
        for (int ni = 0; ni < 2; ni++) {
            const int c = c0 + wn*32 + ni*16 + lr;
            const float bias = is_sig ? bsig[c] : bmu[c];
            #pragma unroll
            for (int mi = 0; mi < 2; mi++) {
                #pragma unroll
                for (int j = 0; j < 4; j++) {
                    const int row = mi*16 + lk*4 + j;
                    const int col = ni*16 + lr;
                    float v = acc[mi][ni][j] + bias;
                    scr[row*40 + col] = is_sig ? __expf(v) : v;
                }
            }
        }
        asm volatile("s_waitcnt lgkmcnt(0)" ::: "memory");

        if (is_sig) {
            if (EXPAND_SIGMA) {
                #pragma unroll 4
                for (int r = 0; r < 32; r++) {
                    size_t base = (size_t)(b0 + wm*32 + r) * 1024
                                + (size_t)(c0 + wn*32) * 4 + lane;
                    #pragma unroll
                    for (int cb = 0; cb < 2; cb++) {
                        float val = scr[r*40 + cb*16 + cidx];
                        f32x4 v;
                        v[0] = (epos == 0) ? val : 0.0f;
                        v[1] = (epos == 1) ? val : 0.0f;
                        v[2] = (epos == 2) ? val : 0.0f;
                        v[3] = (epos == 3) ? val : 0.0f;
                        sig4[base + cb*64] = v;
                    }
                }
            } else {
                // compact: wave's 32 rows x 32 cols -> diag[b][c], 2 rows/instr
                float* dbase = diag + (size_t)(b0 + wm*32)*256 + c0 + wn*32 + cc;
                #pragma unroll
                for (int rr = 0; rr < 16; rr++) {
                    const int row = rr*2 + r2;
                    dbase[(size_t)row*256] = scr[row*40 + cc];
                }
            }
        } else {
            // mu: per it 8 rows x 128B segments, full lines
            #pragma unroll
            for (int it = 0; it < 4; it++) {
                const int r = it*8 + mrr;
                f32x4 v = *reinterpret_cast<const f32x4*>(&scr[r*40 + mcc]);
                size_t base = (size_t)(b0 + wm*32 + r) * 64
                            + (size_t)(c0 + wn*32) / 4 + (lane & 7);
                mu4[base] = v;
            }
        }
    }

    // ---- pi ----
    {
        const short8* Ap = reinterpret_cast<const short8*>(&zs[w*16 + lr][0]);
        const short8* Bp = reinterpret_cast<const short8*>(wsb + WPI_OFF + lr*256);

        f32x4 pacc = {};
        #pragma unroll
        for (int kk = 0; kk < 8; kk++) {
            short8 af = Ap[kk*4 + lk];
            short8 bf = Bp[kk*4 + lk];
            pacc = __builtin_amdgcn_mfma_f32_16x16x32_bf16(af, bf, pacc, 0,0,0);
        }
        const float bp = bpi[lr];
        #pragma unroll
        for (int j = 0; j < 4; j++) {
            float v = pacc[j] + bp;
            float m = v;
            m = fmaxf(m, __shfl_xor(m, 1));
            m = fmaxf(m, __shfl_xor(m, 2));
            m = fmaxf(m, __shfl_xor(m, 4));
            m = fmaxf(m, __shfl_xor(m, 8));
            float e = __expf(v - m);
            float s = e;
            s += __shfl_xor(s, 1);
            s += __shfl_xor(s, 2);
            s += __shfl_xor(s, 4);
            s += __shfl_xor(s, 8);
            const int b = b0 + w*16 + lk*4 + j;
            out_pi[(size_t)b*16 + lr] = e / s;
        }
    }
}

__global__ __launch_bounds__(256, 3) void mdn_full(
    const float* __restrict__ x, const float* __restrict__ W1,
    const float* __restrict__ b1, const float* __restrict__ bpi,
    const float* __restrict__ bsig, const float* __restrict__ bmu,
    const __hip_bfloat16* __restrict__ wsb, float* __restrict__ out)
{
    mdn_body<1>(x, W1, b1, bpi, bsig, bmu, wsb, nullptr, out);
}

__global__ __launch_bounds__(256, 3) void mdn_compact(
    const float* __restrict__ x, const float* __restrict__ W1,
    const float* __restrict__ b1, const float* __restrict__ bpi,
    const float* __restrict__ bsig, const float* __restrict__ bmu,
    const __hip_bfloat16* __restrict__ wsb, float* __restrict__ diag,
    float* __restrict__ out)
{
    mdn_body<0>(x, W1, b1, bpi, bsig, bmu, wsb, diag, out);
}

// ---------------------------------------------------------------------------
// K2: pure expansion, fillBuffer-like stream structure.
// 512 blocks x 4 waves = 2048 streams; each wave: 32 consecutive rows =
// 512KB written fully sequentially (reads also sequential). Next-row value
// prefetch hides the 16 row-loads under the previous row's 16 stores.
// ---------------------------------------------------------------------------
__global__ __launch_bounds__(256) void sigma_expand(
    const float* __restrict__ diag, float* __restrict__ out_sig)
{
    const int t = threadIdx.x;
    const int w = t >> 6, lane = t & 63;
    const int i    = lane >> 2;              // sigma row index within 16x16
    const int epos = i - 4*(lane & 3);       // nonzero slot if in [0,4)
    const int wid  = blockIdx.x * 4 + w;     // 0..2047
    const int b0   = wid * 32;               // 32 consecutive rows per wave

    f32x4* const sig4 = reinterpret_cast<f32x4*>(out_sig);

    float vals[16], nvals[16];
    {
        const float* drow = diag + (size_t)b0*256 + i;
        #pragma unroll
        for (int qq = 0; qq < 16; qq++) vals[qq] = drow[qq*16];
    }
    for (int r = 0; r < 32; r++) {
        const int b = b0 + r;
        // prefetch next row while storing this one
        if (r < 31) {
            const float* drow = diag + (size_t)(b+1)*256 + i;
            #pragma unroll
            for (int qq = 0; qq < 16; qq++) nvals[qq] = drow[qq*16];
        }
        const size_t o4 = (size_t)b*1024 + lane;
        #pragma unroll
        for (int qq = 0; qq < 16; qq++) {
            f32x4 v;
            v[0] = (epos == 0) ? vals[qq] : 0.0f;
            v[1] = (epos == 1) ? vals[qq] : 0.0f;
            v[2] = (epos == 2) ? vals[qq] : 0.0f;
            v[3] = (epos == 3) ? vals[qq] : 0.0f;
            sig4[o4 + qq*64] = v;
        }
        #pragma unroll
        for (int qq = 0; qq < 16; qq++) vals[qq] = nvals[qq];
    }
}

extern "C" void kernel_launch(void* const* d_in, const int* in_sizes, int n_in,
                              void* d_out, int out_size, void* d_ws, size_t ws_size,
                              hipStream_t stream) {
    (void)in_sizes; (void)n_in; (void)out_size;
    const float* x    = (const float*)d_in[0];
    const float* W1   = (const float*)d_in[1];
    const float* b1   = (const float*)d_in[2];
    const float* Wpi  = (const float*)d_in[3];
    const float* bpi  = (const float*)d_in[4];
    const float* Wsig = (const float*)d_in[5];
    const float* bsig = (const float*)d_in[6];
    const float* Wmu  = (const float*)d_in[7];
    const float* bmu  = (const float*)d_in[8];
    float* out = (float*)d_out;
    __hip_bfloat16* wsb = (__hip_bfloat16*)d_ws;

    cvt_weights<<<528, 256, 0, stream>>>(Wpi, Wsig, Wmu, wsb);

    if (ws_size >= WS_WEIGHT_BYTES + WS_DIAG_BYTES) {
        float* diag = (float*)((char*)d_ws + WS_WEIGHT_BYTES);
        mdn_compact<<<NB/TB, 256, 0, stream>>>(x, W1, b1, bpi, bsig, bmu,
                                               wsb, diag, out);
        sigma_expand<<<512, 256, 0, stream>>>(diag, out + (size_t)NB*16);
    } else {
        mdn_full<<<NB/TB, 256, 0, stream>>>(x, W1, b1, bpi, bsig, bmu,
                                            wsb, out);
    }
}